// Round 5
// baseline (746.284 us; speedup 1.0000x reference)
//
#include <hip/hip_runtime.h>

#define NN 1024
#define FF 64
#define CC 4
#define EE 32768
#define HH 256

// ---- workspace layout (units of 4-byte words) ----
// zeroed region (one memset): adense + cnt + mask + npairs
#define OFF_ADENSE 0u         // 4194304 f  (N*N*C)
#define OFF_CNT    4194304u   // 4096 i
#define OFF_MASK   4198400u   // 32768 u32 (1 bit per (i,j) pair)
#define OFF_NPAIRS 4231168u   // 4 i (1 used)
// ---- end of zero region: 4231172 words
#define OFF_OFFS   4231172u   // 4097 i
#define OFF_CURSOR 4235272u   // 4096 i
#define OFF_SRTS   4239368u   // 131072 i
#define OFF_SRTW   4370440u   // 131072 f
#define OFF_P      4501512u   // 262144 f
#define OFF_Q      4763656u   // 262144 f
#define OFF_PLIST  5025800u   // 131072 i  (unique nonzero pairs)
// end 5156872 words = 20.6 MB

// ---------------------------------------------------------------------------
// S1: bucket counts per (c, dst)
__global__ __launch_bounds__(256)
void k_count(const int* __restrict__ ei, int* __restrict__ cnt)
{
    unsigned t = blockIdx.x * 256u + threadIdx.x;   // t < C*E
    unsigned e = t & (EE - 1u);
    unsigned c = t >> 15;
    int dst = ei[c * 2 * EE + EE + e];
    atomicAdd(&cnt[c * NN + dst], 1);
}

// S2: exclusive prefix sum over 4096 counts. 256 threads x 16 counts,
// wave-shfl scan, single barrier.
__global__ __launch_bounds__(256)
void k_scan(const int* __restrict__ cnt, int* __restrict__ offs, int* __restrict__ cursor)
{
    __shared__ int wsum[4];
    const int t = threadIdx.x;
    int c[16];
    int s = 0;
    const int4* cp = (const int4*)(cnt + t * 16);
#pragma unroll
    for (int u = 0; u < 4; ++u) {
        int4 v = cp[u];
        c[u * 4 + 0] = v.x; c[u * 4 + 1] = v.y; c[u * 4 + 2] = v.z; c[u * 4 + 3] = v.w;
        s += v.x + v.y + v.z + v.w;
    }
    int incl = s;
#pragma unroll
    for (int d = 1; d < 64; d <<= 1) {
        int v = __shfl_up(incl, d, 64);
        if ((t & 63) >= d) incl += v;
    }
    const int w = t >> 6;
    if ((t & 63) == 63) wsum[w] = incl;
    __syncthreads();
    int base = incl - s;                    // exclusive within wave
    for (int ww = 0; ww < w; ++ww) base += wsum[ww];
    int run = base;
#pragma unroll
    for (int u = 0; u < 16; ++u) {
        offs[t * 16 + u] = run;
        cursor[t * 16 + u] = run;
        run += c[u];
    }
    if (t == 255) offs[4096] = run;
}

// S3: bucket-scatter edges + dense adjacency atomics + unique-pair list.
// mask is 1 bit per (src,dst) pair; first setter appends to plist.
__global__ __launch_bounds__(256)
void k_bucket_adj(const int* __restrict__ ei, const float* __restrict__ ew,
                  int* __restrict__ cursor, int* __restrict__ srt_src,
                  float* __restrict__ srt_w, float* __restrict__ adense,
                  unsigned* __restrict__ mask, int* __restrict__ plist,
                  int* __restrict__ npairs)
{
    unsigned t = blockIdx.x * 256u + threadIdx.x;
    unsigned e = t & (EE - 1u);
    unsigned c = t >> 15;
    int src = ei[c * 2 * EE + e];
    int dst = ei[c * 2 * EE + EE + e];
    float w = ew[c * EE + e];
    int pos = atomicAdd(&cursor[c * NN + dst], 1);
    srt_src[pos] = src;
    srt_w[pos] = w;
    unsigned pair = (unsigned)src * NN + (unsigned)dst;
    atomicAdd(&adense[(size_t)pair * CC + c], w);
    unsigned bit = 1u << (pair & 31u);
    unsigned old = atomicOr(&mask[pair >> 5], bit);
    if (!(old & bit)) {
        int q = atomicAdd(npairs, 1);
        plist[q] = (int)pair;
    }
}

// ---------------------------------------------------------------------------
// Fused node pipeline: gather -> mlp1 -> mlp2 -> P/Q. 4 nodes per 1024-thread
// block; agg/hid/xn live only in LDS.
__global__ __launch_bounds__(1024)
void k_node(const float* __restrict__ x, const int* __restrict__ offs,
            const int* __restrict__ srt_src, const float* __restrict__ srt_w,
            const float* __restrict__ Wn1, const float* __restrict__ bn1,
            const float* __restrict__ Wn2, const float* __restrict__ bn2,
            const float* __restrict__ We1, const float* __restrict__ be1,
            const float* __restrict__ epsp,
            float* __restrict__ P, float* __restrict__ Q)
{
    __shared__ float hval[4][256];
    __shared__ float hidl[4][256];
    __shared__ float part[4][4][64];
    __shared__ float xnl[4][64];
    const int tid = threadIdx.x;
    const int n0 = blockIdx.x * 4;

    // gather: wave w handles bucket (c = w&3, node = n0 + (w>>2)), lane = f
    {
        const int w = tid >> 6, lane = tid & 63;
        const int c = w & 3, nn = w >> 2;
        const int g = c * NN + (n0 + nn);
        const int beg = offs[g], end = offs[g + 1];
        float acc = 0.f;
        for (int k = beg; k < end; ++k)
            acc += x[srt_src[k] * FF + lane] * srt_w[k];
        const float ope = 1.0f + epsp[0];
        hval[nn][c * 64 + lane] = acc + ope * x[(n0 + nn) * FF + lane];
    }
    __syncthreads();

    // mlp1: hid[nn][h] = relu(bn1[h] + sum_k hval[nn][k] * Wn1[k][h])
    {
        const int nn = tid >> 8, h = tid & 255;
        float acc = bn1[h];
#pragma unroll 8
        for (int k = 0; k < 256; ++k)
            acc += hval[nn][k] * Wn1[k * 256 + h];
        hidl[nn][h] = fmaxf(acc, 0.f);
    }
    __syncthreads();

    // mlp2 partials over 4 k-quarters
    {
        const int kq = tid >> 8, nn = (tid >> 6) & 3, f = tid & 63;
        float p = 0.f;
#pragma unroll 8
        for (int k = kq * 64; k < kq * 64 + 64; ++k)
            p += hidl[nn][k] * Wn2[k * 64 + f];
        part[kq][nn][f] = p;
    }
    __syncthreads();
    if (tid < 256) {
        const int nn = tid >> 6, f = tid & 63;
        xnl[nn][f] = bn2[f] + part[0][nn][f] + part[1][nn][f]
                             + part[2][nn][f] + part[3][nn][f];
    }
    __syncthreads();

    // P/Q projection
    {
        const int r = tid >> 8, h = tid & 255;
        float p = be1[h], q = 0.f;
#pragma unroll 8
        for (int f = 0; f < 64; ++f) {
            float xv = xnl[r][f];
            p += xv * We1[(4 + f) * 256 + h];
            q += xv * We1[(68 + f) * 256 + h];
        }
        P[(n0 + r) * 256 + h] = p;
        Q[(n0 + r) * 256 + h] = q;
    }
}

// ---------------------------------------------------------------------------
// Pass A (dense): out[i][j][o] = be2[o] + sum_h relu(P[i][h]+Q[j][h]) * We2[h][o]
// — exact for the ~88% of pairs with a == 0; nonzero pairs are overwritten by
// k_edge_fix. Same compute as round 4 (32x32 tile, 2x2/thread, grid 32x32).
// EPILOGUE CHANGE: rounds 2-4 all showed 50-76x HBM write amplification
// (partial-line RMW signature: FETCH ~= WRITE/2) regardless of store flavor or
// geometry. Here the output tile is staged in LDS (reusing dead Pl/Ql — zero
// extra LDS) and written with lane-consecutive float4 stores, so every 128-B
// line is produced entirely by 8 lanes of ONE instruction — no dependence on
// downstream write-combining at all.
__global__ __launch_bounds__(256, 4)
void k_edge_base(const float* __restrict__ P, const float* __restrict__ Q,
                 const float* __restrict__ We2, const float* __restrict__ be2,
                 float* __restrict__ out)
{
    __shared__ float4 Pl[32 * 16];   // 8 KB: [row][quad ^ ((row>>1)&7)]
    __shared__ float4 Ql[32 * 16];   // 8 KB

    const int tid = threadIdx.x;
    const int tx = tid & 15, ty = tid >> 4;
    const int iBase = blockIdx.y * 32, jBase = blockIdx.x * 32;
    const int psw = ty & 7;
    const int qsw = tx & 7;

    const float4 b2 = *(const float4*)be2;
    float4 acc[2][2];
#pragma unroll
    for (int ii = 0; ii < 2; ++ii)
#pragma unroll
        for (int jj = 0; jj < 2; ++jj)
            acc[ii][jj] = b2;

    for (int hc = 0; hc < 4; ++hc) {
        __syncthreads();
#pragma unroll
        for (int u = 0; u < 2; ++u) {
            int idx = tid + u * 256;
            int row = idx >> 4, q = idx & 15;
            int ph = q ^ ((row >> 1) & 7);
            Pl[row * 16 + ph] = *(const float4*)(P + (iBase + row) * 256 + hc * 64 + q * 4);
            Ql[row * 16 + ph] = *(const float4*)(Q + (jBase + row) * 256 + hc * 64 + q * 4);
        }
        __syncthreads();

#pragma unroll
        for (int q = 0; q < 16; ++q) {
            // wave-uniform weight loads -> scalar pipe
            float4 w2[4];
#pragma unroll
            for (int k = 0; k < 4; ++k)
                w2[k] = *(const float4*)(We2 + (hc * 64 + q * 4 + k) * 4);

            float4 p[2], qv[2];
#pragma unroll
            for (int r = 0; r < 2; ++r) p[r]  = Pl[(ty * 2 + r) * 16 + (q ^ psw)];
#pragma unroll
            for (int r = 0; r < 2; ++r) qv[r] = Ql[(tx * 2 + r) * 16 + (q ^ qsw)];

#pragma unroll
            for (int ii = 0; ii < 2; ++ii) {
#pragma unroll
                for (int jj = 0; jj < 2; ++jj) {
                    float v0 = fmaxf(p[ii].x + qv[jj].x, 0.f);
                    float v1 = fmaxf(p[ii].y + qv[jj].y, 0.f);
                    float v2 = fmaxf(p[ii].z + qv[jj].z, 0.f);
                    float v3 = fmaxf(p[ii].w + qv[jj].w, 0.f);
                    acc[ii][jj].x += v0 * w2[0].x + v1 * w2[1].x + v2 * w2[2].x + v3 * w2[3].x;
                    acc[ii][jj].y += v0 * w2[0].y + v1 * w2[1].y + v2 * w2[2].y + v3 * w2[3].y;
                    acc[ii][jj].z += v0 * w2[0].z + v1 * w2[1].z + v2 * w2[2].z + v3 * w2[3].z;
                    acc[ii][jj].w += v0 * w2[0].w + v1 * w2[1].w + v2 * w2[2].w + v3 * w2[3].w;
                }
            }
        }
    }

    // stage output tile (32x32 float4 = 16 KB) into Pl/Ql, then write
    // wave-contiguous: flat F = r*32 + c; F < 512 -> Pl, else Ql.
    __syncthreads();                      // all Pl/Ql reads done
#pragma unroll
    for (int ii = 0; ii < 2; ++ii)
#pragma unroll
        for (int jj = 0; jj < 2; ++jj) {
            int F = (ty * 2 + ii) * 32 + (tx * 2 + jj);
            if (F < 512) Pl[F] = acc[ii][jj];   // wave-uniform branch (ty<8)
            else         Ql[F - 512] = acc[ii][jj];
        }
    __syncthreads();
#pragma unroll
    for (int k = 0; k < 4; ++k) {
        int F = k * 256 + tid;                  // lane-consecutive
        float4 v = (k < 2) ? Pl[F & 511] : Ql[F & 511];
        int r = F >> 5, c = F & 31;
        *(float4*)(out + ((size_t)(iBase + r) * NN + (jBase + c)) * 4) = v;
    }
}

// ---------------------------------------------------------------------------
// Pass B (sparse fix-up): recompute the ~12% of pairs with nonzero adjacency,
// including the a*We1 term, and overwrite. One pair per wave; lane owns
// h = lane, lane+64, lane+128, lane+192; shfl tree-reduce the 4 outputs.
// P/Q/We1/We2 are L2-resident (2 MB + 132 KB).
__global__ __launch_bounds__(256)
void k_edge_fix(const float* __restrict__ P, const float* __restrict__ Q,
                const float* __restrict__ adense, const float* __restrict__ We1,
                const float* __restrict__ We2, const float* __restrict__ be2,
                const int* __restrict__ plist, const int* __restrict__ npairs,
                float* __restrict__ out)
{
    const int lane = threadIdx.x & 63;
    const int wid = (blockIdx.x << 2) | (threadIdx.x >> 6);
    const int nw = gridDim.x << 2;
    const int n = npairs[0];
    const float4 b2 = *(const float4*)be2;

    for (int pidx = wid; pidx < n; pidx += nw) {
        const int pair = plist[pidx];
        const int i = pair >> 10, j = pair & (NN - 1);
        const float4 a = *(const float4*)(adense + (size_t)pair * 4);
        float o0 = 0.f, o1 = 0.f, o2 = 0.f, o3 = 0.f;
#pragma unroll
        for (int u = 0; u < 4; ++u) {
            const int h = u * 64 + lane;
            float s = a.x * We1[0 * 256 + h] + a.y * We1[1 * 256 + h]
                    + a.z * We1[2 * 256 + h] + a.w * We1[3 * 256 + h];
            float v = fmaxf(P[i * 256 + h] + Q[j * 256 + h] + s, 0.f);
            const float4 w2 = *(const float4*)(We2 + h * 4);
            o0 += v * w2.x; o1 += v * w2.y; o2 += v * w2.z; o3 += v * w2.w;
        }
#pragma unroll
        for (int d = 32; d > 0; d >>= 1) {
            o0 += __shfl_down(o0, d, 64);
            o1 += __shfl_down(o1, d, 64);
            o2 += __shfl_down(o2, d, 64);
            o3 += __shfl_down(o3, d, 64);
        }
        if (lane == 0)
            *(float4*)(out + (size_t)pair * 4) =
                make_float4(o0 + b2.x, o1 + b2.y, o2 + b2.z, o3 + b2.w);
    }
}

// ---------------------------------------------------------------------------
extern "C" void kernel_launch(void* const* d_in, const int* in_sizes, int n_in,
                              void* d_out, int out_size, void* d_ws, size_t ws_size,
                              hipStream_t stream)
{
    (void)in_sizes; (void)n_in; (void)out_size; (void)ws_size;
    const float* x   = (const float*)d_in[0];
    const int*   ei  = (const int*)d_in[1];
    const float* ew  = (const float*)d_in[2];
    const float* Wn1 = (const float*)d_in[3];
    const float* bn1 = (const float*)d_in[4];
    const float* Wn2 = (const float*)d_in[5];
    const float* bn2 = (const float*)d_in[6];
    const float* We1 = (const float*)d_in[7];
    const float* be1 = (const float*)d_in[8];
    const float* We2 = (const float*)d_in[9];
    const float* be2 = (const float*)d_in[10];
    const float* eps = (const float*)d_in[11];
    float* out = (float*)d_out;

    float*    ws     = (float*)d_ws;
    float*    adense = ws + OFF_ADENSE;
    int*      cnt    = (int*)(ws + OFF_CNT);
    unsigned* mask   = (unsigned*)(ws + OFF_MASK);
    int*      npair  = (int*)(ws + OFF_NPAIRS);
    int*      offs   = (int*)(ws + OFF_OFFS);
    int*      cursor = (int*)(ws + OFF_CURSOR);
    int*      srts   = (int*)(ws + OFF_SRTS);
    float*    srtw   = ws + OFF_SRTW;
    float*    Pb     = ws + OFF_P;
    float*    Qb     = ws + OFF_Q;
    int*      plist  = (int*)(ws + OFF_PLIST);

    // zero adense + cnt + mask + npairs (contiguous)
    (void)hipMemsetAsync(d_ws, 0, (size_t)4231172 * sizeof(float), stream);

    k_count     <<<(CC * EE) / 256, 256, 0, stream>>>(ei, cnt);
    k_scan      <<<1, 256, 0, stream>>>(cnt, offs, cursor);
    k_bucket_adj<<<(CC * EE) / 256, 256, 0, stream>>>(ei, ew, cursor, srts, srtw,
                                                      adense, mask, plist, npair);
    k_node      <<<NN / 4, 1024, 0, stream>>>(x, offs, srts, srtw,
                                              Wn1, bn1, Wn2, bn2, We1, be1, eps, Pb, Qb);

    dim3 gb(NN / 32, NN / 32);
    k_edge_base<<<gb, 256, 0, stream>>>(Pb, Qb, We2, be2, out);
    k_edge_fix <<<2048, 256, 0, stream>>>(Pb, Qb, adense, We1, We2, be2,
                                          plist, npair, out);
}

// Round 6
// 237.612 us; speedup vs baseline: 3.1408x; 3.1408x over previous
//
#include <hip/hip_runtime.h>

#define NN 1024
#define FF 64
#define CC 4
#define EE 32768
#define HH 256

// ---- workspace layout (units of 4-byte words) ----
#define OFF_ADENSE 0u         // 4194304 f  (N*N*C)
#define OFF_CNT    4194304u   // 4096 i  (memset together with adense)
#define OFF_OFFS   4198400u   // 4097 i
#define OFF_CURSOR 4202512u   // 4096 i
#define OFF_SRTS   4206608u   // 131072 i
#define OFF_SRTW   4337680u   // 131072 f
#define OFF_P      4468752u   // 262144 f
#define OFF_Q      4730896u   // 262144 f
// end 4993040 words = 20.0 MB

// ---------------------------------------------------------------------------
// S1: bucket counts per (c, dst)
__global__ __launch_bounds__(256)
void k_count(const int* __restrict__ ei, int* __restrict__ cnt)
{
    unsigned t = blockIdx.x * 256u + threadIdx.x;   // t < C*E
    unsigned e = t & (EE - 1u);
    unsigned c = t >> 15;
    int dst = ei[c * 2 * EE + EE + e];
    atomicAdd(&cnt[c * NN + dst], 1);
}

// S2: exclusive prefix sum over 4096 counts. 256 threads x 16 counts,
// wave-shfl scan, single barrier.
__global__ __launch_bounds__(256)
void k_scan(const int* __restrict__ cnt, int* __restrict__ offs, int* __restrict__ cursor)
{
    __shared__ int wsum[4];
    const int t = threadIdx.x;
    int c[16];
    int s = 0;
    const int4* cp = (const int4*)(cnt + t * 16);
#pragma unroll
    for (int u = 0; u < 4; ++u) {
        int4 v = cp[u];
        c[u * 4 + 0] = v.x; c[u * 4 + 1] = v.y; c[u * 4 + 2] = v.z; c[u * 4 + 3] = v.w;
        s += v.x + v.y + v.z + v.w;
    }
    int incl = s;
#pragma unroll
    for (int d = 1; d < 64; d <<= 1) {
        int v = __shfl_up(incl, d, 64);
        if ((t & 63) >= d) incl += v;
    }
    const int w = t >> 6;
    if ((t & 63) == 63) wsum[w] = incl;
    __syncthreads();
    int base = incl - s;                    // exclusive within wave
    for (int ww = 0; ww < w; ++ww) base += wsum[ww];
    int run = base;
#pragma unroll
    for (int u = 0; u < 16; ++u) {
        offs[t * 16 + u] = run;
        cursor[t * 16 + u] = run;
        run += c[u];
    }
    if (t == 255) offs[4096] = run;
}

// S3: bucket-scatter edges + dense adjacency atomics (fused edge pass)
__global__ __launch_bounds__(256)
void k_bucket_adj(const int* __restrict__ ei, const float* __restrict__ ew,
                  int* __restrict__ cursor, int* __restrict__ srt_src,
                  float* __restrict__ srt_w, float* __restrict__ adense)
{
    unsigned t = blockIdx.x * 256u + threadIdx.x;
    unsigned e = t & (EE - 1u);
    unsigned c = t >> 15;
    int src = ei[c * 2 * EE + e];
    int dst = ei[c * 2 * EE + EE + e];
    float w = ew[c * EE + e];
    int pos = atomicAdd(&cursor[c * NN + dst], 1);
    srt_src[pos] = src;
    srt_w[pos] = w;
    atomicAdd(&adense[((size_t)src * NN + dst) * CC + c], w);
}

// ---------------------------------------------------------------------------
// Fused node pipeline: gather -> mlp1 -> mlp2 -> P/Q. 4 nodes per 1024-thread
// block; agg/hid/xn live only in LDS.
__global__ __launch_bounds__(1024)
void k_node(const float* __restrict__ x, const int* __restrict__ offs,
            const int* __restrict__ srt_src, const float* __restrict__ srt_w,
            const float* __restrict__ Wn1, const float* __restrict__ bn1,
            const float* __restrict__ Wn2, const float* __restrict__ bn2,
            const float* __restrict__ We1, const float* __restrict__ be1,
            const float* __restrict__ epsp,
            float* __restrict__ P, float* __restrict__ Q)
{
    __shared__ float hval[4][256];
    __shared__ float hidl[4][256];
    __shared__ float part[4][4][64];
    __shared__ float xnl[4][64];
    const int tid = threadIdx.x;
    const int n0 = blockIdx.x * 4;

    // gather: wave w handles bucket (c = w&3, node = n0 + (w>>2)), lane = f
    {
        const int w = tid >> 6, lane = tid & 63;
        const int c = w & 3, nn = w >> 2;
        const int g = c * NN + (n0 + nn);
        const int beg = offs[g], end = offs[g + 1];
        float acc = 0.f;
        for (int k = beg; k < end; ++k)
            acc += x[srt_src[k] * FF + lane] * srt_w[k];
        const float ope = 1.0f + epsp[0];
        hval[nn][c * 64 + lane] = acc + ope * x[(n0 + nn) * FF + lane];
    }
    __syncthreads();

    // mlp1: hid[nn][h] = relu(bn1[h] + sum_k hval[nn][k] * Wn1[k][h])
    {
        const int nn = tid >> 8, h = tid & 255;
        float acc = bn1[h];
#pragma unroll 8
        for (int k = 0; k < 256; ++k)
            acc += hval[nn][k] * Wn1[k * 256 + h];
        hidl[nn][h] = fmaxf(acc, 0.f);
    }
    __syncthreads();

    // mlp2 partials over 4 k-quarters
    {
        const int kq = tid >> 8, nn = (tid >> 6) & 3, f = tid & 63;
        float p = 0.f;
#pragma unroll 8
        for (int k = kq * 64; k < kq * 64 + 64; ++k)
            p += hidl[nn][k] * Wn2[k * 64 + f];
        part[kq][nn][f] = p;
    }
    __syncthreads();
    if (tid < 256) {
        const int nn = tid >> 6, f = tid & 63;
        xnl[nn][f] = bn2[f] + part[0][nn][f] + part[1][nn][f]
                             + part[2][nn][f] + part[3][nn][f];
    }
    __syncthreads();

    // P/Q projection
    {
        const int r = tid >> 8, h = tid & 255;
        float p = be1[h], q = 0.f;
#pragma unroll 8
        for (int f = 0; f < 64; ++f) {
            float xv = xnl[r][f];
            p += xv * We1[(4 + f) * 256 + h];
            q += xv * We1[(68 + f) * 256 + h];
        }
        P[(n0 + r) * 256 + h] = p;
        Q[(n0 + r) * 256 + h] = q;
    }
}

// ---------------------------------------------------------------------------
// out[i][j][o] = be2[o] + sum_h relu(P[i][h]+Q[j][h]+sum_c a[i][j][c]*We1[c][h]) * We2[h][o]
// 32x32 pair tile, 1024 blocks (4/CU), 2x2 pairs/thread, H chunked 4x64.
// Weights read via wave-uniform GLOBAL indices -> scalar loads (s_load),
// keeping the LDS pipe for P/Q only (4 ds_read_b128 per thread-q, was 12).
__global__ __launch_bounds__(256, 4)
void k_edge_mlp(const float* __restrict__ P, const float* __restrict__ Q,
                const float* __restrict__ adense, const float* __restrict__ We1,
                const float* __restrict__ We2, const float* __restrict__ be2,
                float* __restrict__ out)
{
    __shared__ float4 Pl[32 * 16];   // 8 KB: [row][quad ^ ((row>>1)&7)]
    __shared__ float4 Ql[32 * 16];   // 8 KB

    const int tid = threadIdx.x;
    const int tx = tid & 15, ty = tid >> 4;
    const int iBase = blockIdx.y * 32, jBase = blockIdx.x * 32;
    const int psw = ty & 7;
    const int qsw = tx & 7;

    float4 a[2][2], acc[2][2];
#pragma unroll
    for (int ii = 0; ii < 2; ++ii)
#pragma unroll
        for (int jj = 0; jj < 2; ++jj) {
            a[ii][jj] = *(const float4*)(adense +
                ((size_t)(iBase + ty * 2 + ii) * NN + (jBase + tx * 2 + jj)) * 4);
            acc[ii][jj] = make_float4(0.f, 0.f, 0.f, 0.f);
        }

    for (int hc = 0; hc < 4; ++hc) {
        __syncthreads();
#pragma unroll
        for (int u = 0; u < 2; ++u) {
            int idx = tid + u * 256;
            int row = idx >> 4, q = idx & 15;
            int ph = q ^ ((row >> 1) & 7);
            Pl[row * 16 + ph] = *(const float4*)(P + (iBase + row) * 256 + hc * 64 + q * 4);
            Ql[row * 16 + ph] = *(const float4*)(Q + (jBase + row) * 256 + hc * 64 + q * 4);
        }
        __syncthreads();

        for (int q = 0; q < 16; ++q) {
            // wave-uniform weight loads -> scalar pipe
            float4 w1[4], w2[4];
#pragma unroll
            for (int c = 0; c < 4; ++c)
                w1[c] = *(const float4*)(We1 + c * 256 + hc * 64 + q * 4);
#pragma unroll
            for (int k = 0; k < 4; ++k)
                w2[k] = *(const float4*)(We2 + (hc * 64 + q * 4 + k) * 4);

            float4 p[2], qv[2];
#pragma unroll
            for (int r = 0; r < 2; ++r) p[r]  = Pl[(ty * 2 + r) * 16 + (q ^ psw)];
#pragma unroll
            for (int r = 0; r < 2; ++r) qv[r] = Ql[(tx * 2 + r) * 16 + (q ^ qsw)];

#pragma unroll
            for (int ii = 0; ii < 2; ++ii) {
#pragma unroll
                for (int jj = 0; jj < 2; ++jj) {
                    const float4 av = a[ii][jj];
                    float s0 = av.x * w1[0].x + av.y * w1[1].x + av.z * w1[2].x + av.w * w1[3].x;
                    float s1 = av.x * w1[0].y + av.y * w1[1].y + av.z * w1[2].y + av.w * w1[3].y;
                    float s2 = av.x * w1[0].z + av.y * w1[1].z + av.z * w1[2].z + av.w * w1[3].z;
                    float s3 = av.x * w1[0].w + av.y * w1[1].w + av.z * w1[2].w + av.w * w1[3].w;
                    float v0 = fmaxf(p[ii].x + qv[jj].x + s0, 0.f);
                    float v1 = fmaxf(p[ii].y + qv[jj].y + s1, 0.f);
                    float v2 = fmaxf(p[ii].z + qv[jj].z + s2, 0.f);
                    float v3 = fmaxf(p[ii].w + qv[jj].w + s3, 0.f);
                    acc[ii][jj].x += v0 * w2[0].x + v1 * w2[1].x + v2 * w2[2].x + v3 * w2[3].x;
                    acc[ii][jj].y += v0 * w2[0].y + v1 * w2[1].y + v2 * w2[2].y + v3 * w2[3].y;
                    acc[ii][jj].z += v0 * w2[0].z + v1 * w2[1].z + v2 * w2[2].z + v3 * w2[3].z;
                    acc[ii][jj].w += v0 * w2[0].w + v1 * w2[1].w + v2 * w2[2].w + v3 * w2[3].w;
                }
            }
        }
    }

    const float4 b2 = *(const float4*)be2;
#pragma unroll
    for (int ii = 0; ii < 2; ++ii)
#pragma unroll
        for (int jj = 0; jj < 2; ++jj) {
            float4 o = acc[ii][jj];
            o.x += b2.x; o.y += b2.y; o.z += b2.z; o.w += b2.w;
            *(float4*)(out + ((size_t)(iBase + ty * 2 + ii) * NN + (jBase + tx * 2 + jj)) * 4) = o;
        }
}

// ---------------------------------------------------------------------------
extern "C" void kernel_launch(void* const* d_in, const int* in_sizes, int n_in,
                              void* d_out, int out_size, void* d_ws, size_t ws_size,
                              hipStream_t stream)
{
    (void)in_sizes; (void)n_in; (void)out_size; (void)ws_size;
    const float* x   = (const float*)d_in[0];
    const int*   ei  = (const int*)d_in[1];
    const float* ew  = (const float*)d_in[2];
    const float* Wn1 = (const float*)d_in[3];
    const float* bn1 = (const float*)d_in[4];
    const float* Wn2 = (const float*)d_in[5];
    const float* bn2 = (const float*)d_in[6];
    const float* We1 = (const float*)d_in[7];
    const float* be1 = (const float*)d_in[8];
    const float* We2 = (const float*)d_in[9];
    const float* be2 = (const float*)d_in[10];
    const float* eps = (const float*)d_in[11];
    float* out = (float*)d_out;

    float* ws = (float*)d_ws;
    float* adense = ws + OFF_ADENSE;
    int*   cnt    = (int*)(ws + OFF_CNT);
    int*   offs   = (int*)(ws + OFF_OFFS);
    int*   cursor = (int*)(ws + OFF_CURSOR);
    int*   srts   = (int*)(ws + OFF_SRTS);
    float* srtw   = ws + OFF_SRTW;
    float* Pb     = ws + OFF_P;
    float* Qb     = ws + OFF_Q;

    // zero adense + cnt (contiguous)
    (void)hipMemsetAsync(d_ws, 0, (size_t)(4194304 + 4096) * sizeof(float), stream);

    k_count     <<<(CC * EE) / 256, 256, 0, stream>>>(ei, cnt);
    k_scan      <<<1, 256, 0, stream>>>(cnt, offs, cursor);
    k_bucket_adj<<<(CC * EE) / 256, 256, 0, stream>>>(ei, ew, cursor, srts, srtw, adense);
    k_node      <<<NN / 4, 1024, 0, stream>>>(x, offs, srts, srtw,
                                              Wn1, bn1, Wn2, bn2, We1, be1, eps, Pb, Qb);

    dim3 g(NN / 32, NN / 32);
    k_edge_mlp<<<g, 256, 0, stream>>>(Pb, Qb, adense, We1, We2, be2, out);
}

// Round 7
// 229.276 us; speedup vs baseline: 3.2550x; 1.0364x over previous
//
#include <hip/hip_runtime.h>

#define NN 1024
#define FF 64
#define CC 4
#define EE 32768
#define HH 256

// ---- workspace layout (units of 4-byte words) ----
#define OFF_ADENSE 0u         // 4194304 f  (N*N*C)
#define OFF_CNT    4194304u   // 4096 i  (memset together with adense)
#define OFF_OFFS   4198400u   // 4097 i
#define OFF_CURSOR 4202512u   // 4096 i
#define OFF_SRTS   4206608u   // 131072 i
#define OFF_SRTW   4337680u   // 131072 f
#define OFF_P      4468752u   // 262144 f
#define OFF_Q      4730896u   // 262144 f
// end 4993040 words = 20.0 MB

// ---------------------------------------------------------------------------
// S1: bucket counts per (c, dst)
__global__ __launch_bounds__(256)
void k_count(const int* __restrict__ ei, int* __restrict__ cnt)
{
    unsigned t = blockIdx.x * 256u + threadIdx.x;   // t < C*E
    unsigned e = t & (EE - 1u);
    unsigned c = t >> 15;
    int dst = ei[c * 2 * EE + EE + e];
    atomicAdd(&cnt[c * NN + dst], 1);
}

// S2: exclusive prefix sum over 4096 counts. 256 threads x 16 counts,
// wave-shfl scan, single barrier.
__global__ __launch_bounds__(256)
void k_scan(const int* __restrict__ cnt, int* __restrict__ offs, int* __restrict__ cursor)
{
    __shared__ int wsum[4];
    const int t = threadIdx.x;
    int c[16];
    int s = 0;
    const int4* cp = (const int4*)(cnt + t * 16);
#pragma unroll
    for (int u = 0; u < 4; ++u) {
        int4 v = cp[u];
        c[u * 4 + 0] = v.x; c[u * 4 + 1] = v.y; c[u * 4 + 2] = v.z; c[u * 4 + 3] = v.w;
        s += v.x + v.y + v.z + v.w;
    }
    int incl = s;
#pragma unroll
    for (int d = 1; d < 64; d <<= 1) {
        int v = __shfl_up(incl, d, 64);
        if ((t & 63) >= d) incl += v;
    }
    const int w = t >> 6;
    if ((t & 63) == 63) wsum[w] = incl;
    __syncthreads();
    int base = incl - s;                    // exclusive within wave
    for (int ww = 0; ww < w; ++ww) base += wsum[ww];
    int run = base;
#pragma unroll
    for (int u = 0; u < 16; ++u) {
        offs[t * 16 + u] = run;
        cursor[t * 16 + u] = run;
        run += c[u];
    }
    if (t == 255) offs[4096] = run;
}

// S3: bucket-scatter edges + dense adjacency atomics (fused edge pass)
__global__ __launch_bounds__(256)
void k_bucket_adj(const int* __restrict__ ei, const float* __restrict__ ew,
                  int* __restrict__ cursor, int* __restrict__ srt_src,
                  float* __restrict__ srt_w, float* __restrict__ adense)
{
    unsigned t = blockIdx.x * 256u + threadIdx.x;
    unsigned e = t & (EE - 1u);
    unsigned c = t >> 15;
    int src = ei[c * 2 * EE + e];
    int dst = ei[c * 2 * EE + EE + e];
    float w = ew[c * EE + e];
    int pos = atomicAdd(&cursor[c * NN + dst], 1);
    srt_src[pos] = src;
    srt_w[pos] = w;
    atomicAdd(&adense[((size_t)src * NN + dst) * CC + c], w);
}

// ---------------------------------------------------------------------------
// Fused node pipeline: gather -> mlp1 -> mlp2 -> P/Q. 4 nodes per 1024-thread
// block; agg/hid/xn live only in LDS.
__global__ __launch_bounds__(1024)
void k_node(const float* __restrict__ x, const int* __restrict__ offs,
            const int* __restrict__ srt_src, const float* __restrict__ srt_w,
            const float* __restrict__ Wn1, const float* __restrict__ bn1,
            const float* __restrict__ Wn2, const float* __restrict__ bn2,
            const float* __restrict__ We1, const float* __restrict__ be1,
            const float* __restrict__ epsp,
            float* __restrict__ P, float* __restrict__ Q)
{
    __shared__ float hval[4][256];
    __shared__ float hidl[4][256];
    __shared__ float part[4][4][64];
    __shared__ float xnl[4][64];
    const int tid = threadIdx.x;
    const int n0 = blockIdx.x * 4;

    // gather: wave w handles bucket (c = w&3, node = n0 + (w>>2)), lane = f
    {
        const int w = tid >> 6, lane = tid & 63;
        const int c = w & 3, nn = w >> 2;
        const int g = c * NN + (n0 + nn);
        const int beg = offs[g], end = offs[g + 1];
        float acc = 0.f;
        for (int k = beg; k < end; ++k)
            acc += x[srt_src[k] * FF + lane] * srt_w[k];
        const float ope = 1.0f + epsp[0];
        hval[nn][c * 64 + lane] = acc + ope * x[(n0 + nn) * FF + lane];
    }
    __syncthreads();

    // mlp1: hid[nn][h] = relu(bn1[h] + sum_k hval[nn][k] * Wn1[k][h])
    {
        const int nn = tid >> 8, h = tid & 255;
        float acc = bn1[h];
#pragma unroll 8
        for (int k = 0; k < 256; ++k)
            acc += hval[nn][k] * Wn1[k * 256 + h];
        hidl[nn][h] = fmaxf(acc, 0.f);
    }
    __syncthreads();

    // mlp2 partials over 4 k-quarters
    {
        const int kq = tid >> 8, nn = (tid >> 6) & 3, f = tid & 63;
        float p = 0.f;
#pragma unroll 8
        for (int k = kq * 64; k < kq * 64 + 64; ++k)
            p += hidl[nn][k] * Wn2[k * 64 + f];
        part[kq][nn][f] = p;
    }
    __syncthreads();
    if (tid < 256) {
        const int nn = tid >> 6, f = tid & 63;
        xnl[nn][f] = bn2[f] + part[0][nn][f] + part[1][nn][f]
                             + part[2][nn][f] + part[3][nn][f];
    }
    __syncthreads();

    // P/Q projection
    {
        const int r = tid >> 8, h = tid & 255;
        float p = be1[h], q = 0.f;
#pragma unroll 8
        for (int f = 0; f < 64; ++f) {
            float xv = xnl[r][f];
            p += xv * We1[(4 + f) * 256 + h];
            q += xv * We1[(68 + f) * 256 + h];
        }
        P[(n0 + r) * 256 + h] = p;
        Q[(n0 + r) * 256 + h] = q;
    }
}

// ---------------------------------------------------------------------------
// out[i][j][o] = be2[o] + sum_h relu(P[i][h]+Q[j][h]+sum_c a[i][j][c]*We1[c][h]) * We2[h][o]
// 32x32 pair tile, 1024 blocks (4/CU), 2x2 pairs/thread, H chunked 4x64.
// SPARSE-AWARE single kernel (kernel sequence and store stream IDENTICAL to
// the 237µs baseline — the two-pass variants of rounds 2-5 all triggered an
// unexplained 50-76x HBM write amplification and are abandoned):
//   1. tile-local LDS list of pairs with nonzero a (~126 of 1024; list sized
//      1024 so it cannot overflow)
//   2. main loop drops the a*We1 dot (44 -> 28 VALU per pair-quad) — exact
//      for the ~88% zero-a pairs
//   3. after the main loop the 4 waves cooperatively recompute listed pairs
//      with the full formula (lane-over-h, shfl tree-reduce) into the dead
//      Pl/Ql LDS; owner threads replace their acc before the unchanged store.
__global__ __launch_bounds__(256, 4)
void k_edge_mlp(const float* __restrict__ P, const float* __restrict__ Q,
                const float* __restrict__ adense, const float* __restrict__ We1,
                const float* __restrict__ We2, const float* __restrict__ be2,
                float* __restrict__ out)
{
    __shared__ float4 SMEM[1024];   // 16 KB: [0..511]=Pl, [512..1023]=Ql; then delta tile
    __shared__ int nzlist[1024];    // 4 KB
    __shared__ int lcnt;

    const int tid = threadIdx.x;
    const int tx = tid & 15, ty = tid >> 4;
    const int iBase = blockIdx.y * 32, jBase = blockIdx.x * 32;
    const int psw = ty & 7;
    const int qsw = tx & 7;

    if (tid == 0) lcnt = 0;
    __syncthreads();

    // load a, build nonzero-pair list
    unsigned nzmask = 0;
    float4 acc[2][2];
#pragma unroll
    for (int ii = 0; ii < 2; ++ii)
#pragma unroll
        for (int jj = 0; jj < 2; ++jj) {
            float4 av = *(const float4*)(adense +
                ((size_t)(iBase + ty * 2 + ii) * NN + (jBase + tx * 2 + jj)) * 4);
            if (av.x != 0.f || av.y != 0.f || av.z != 0.f || av.w != 0.f) {
                nzmask |= 1u << (ii * 2 + jj);
                int idx = atomicAdd(&lcnt, 1);
                nzlist[idx] = (ty * 2 + ii) * 32 + (tx * 2 + jj);
            }
            acc[ii][jj] = make_float4(0.f, 0.f, 0.f, 0.f);
        }

    // dense base pass: v = relu(p + q), acc += v * We2
    for (int hc = 0; hc < 4; ++hc) {
        __syncthreads();
#pragma unroll
        for (int u = 0; u < 2; ++u) {
            int idx = tid + u * 256;
            int row = idx >> 4, q = idx & 15;
            int ph = q ^ ((row >> 1) & 7);
            SMEM[row * 16 + ph]       = *(const float4*)(P + (iBase + row) * 256 + hc * 64 + q * 4);
            SMEM[512 + row * 16 + ph] = *(const float4*)(Q + (jBase + row) * 256 + hc * 64 + q * 4);
        }
        __syncthreads();

        for (int q = 0; q < 16; ++q) {
            // wave-uniform weight loads -> scalar pipe
            float4 w2[4];
#pragma unroll
            for (int k = 0; k < 4; ++k)
                w2[k] = *(const float4*)(We2 + (hc * 64 + q * 4 + k) * 4);

            float4 p[2], qv[2];
#pragma unroll
            for (int r = 0; r < 2; ++r) p[r]  = SMEM[(ty * 2 + r) * 16 + (q ^ psw)];
#pragma unroll
            for (int r = 0; r < 2; ++r) qv[r] = SMEM[512 + (tx * 2 + r) * 16 + (q ^ qsw)];

#pragma unroll
            for (int ii = 0; ii < 2; ++ii) {
#pragma unroll
                for (int jj = 0; jj < 2; ++jj) {
                    float v0 = fmaxf(p[ii].x + qv[jj].x, 0.f);
                    float v1 = fmaxf(p[ii].y + qv[jj].y, 0.f);
                    float v2 = fmaxf(p[ii].z + qv[jj].z, 0.f);
                    float v3 = fmaxf(p[ii].w + qv[jj].w, 0.f);
                    acc[ii][jj].x += v0 * w2[0].x + v1 * w2[1].x + v2 * w2[2].x + v3 * w2[3].x;
                    acc[ii][jj].y += v0 * w2[0].y + v1 * w2[1].y + v2 * w2[2].y + v3 * w2[3].y;
                    acc[ii][jj].z += v0 * w2[0].z + v1 * w2[1].z + v2 * w2[2].z + v3 * w2[3].z;
                    acc[ii][jj].w += v0 * w2[0].w + v1 * w2[1].w + v2 * w2[2].w + v3 * w2[3].w;
                }
            }
        }
    }

    // sparse fix pass: full recompute of listed pairs into SMEM (Pl/Ql dead).
    // wave wv handles pairs wv, wv+4, ...; lane owns h = lane + u*64.
    __syncthreads();                       // SMEM reads done; list complete
    {
        const int wv = tid >> 6, lane = tid & 63;
        const int nfix = lcnt;
        for (int pi = wv; pi < nfix; pi += 4) {
            const int lij = nzlist[pi];
            const int gi = iBase + (lij >> 5), gj = jBase + (lij & 31);
            const float4 a = *(const float4*)(adense + ((size_t)gi * NN + gj) * 4);
            float o0 = 0.f, o1 = 0.f, o2 = 0.f, o3 = 0.f;
#pragma unroll
            for (int u = 0; u < 4; ++u) {
                const int h = u * 64 + lane;
                float s = a.x * We1[0 * 256 + h] + a.y * We1[1 * 256 + h]
                        + a.z * We1[2 * 256 + h] + a.w * We1[3 * 256 + h];
                float v = fmaxf(P[gi * 256 + h] + Q[gj * 256 + h] + s, 0.f);
                const float4 w2 = *(const float4*)(We2 + h * 4);
                o0 += v * w2.x; o1 += v * w2.y; o2 += v * w2.z; o3 += v * w2.w;
            }
#pragma unroll
            for (int d = 32; d > 0; d >>= 1) {
                o0 += __shfl_down(o0, d, 64);
                o1 += __shfl_down(o1, d, 64);
                o2 += __shfl_down(o2, d, 64);
                o3 += __shfl_down(o3, d, 64);
            }
            if (lane == 0)
                SMEM[lij] = make_float4(o0, o1, o2, o3);
        }
    }
    __syncthreads();

    // owners replace acc for their nonzero pairs, then store (identical
    // store addressing to baseline: one float4 per pair, written once)
    const float4 b2 = *(const float4*)be2;
#pragma unroll
    for (int ii = 0; ii < 2; ++ii)
#pragma unroll
        for (int jj = 0; jj < 2; ++jj) {
            const int lij = (ty * 2 + ii) * 32 + (tx * 2 + jj);
            const float4 fx = SMEM[lij];
            float4 o = (nzmask & (1u << (ii * 2 + jj))) ? fx : acc[ii][jj];
            o.x += b2.x; o.y += b2.y; o.z += b2.z; o.w += b2.w;
            *(float4*)(out + ((size_t)(iBase + ty * 2 + ii) * NN + (jBase + tx * 2 + jj)) * 4) = o;
        }
}

// ---------------------------------------------------------------------------
extern "C" void kernel_launch(void* const* d_in, const int* in_sizes, int n_in,
                              void* d_out, int out_size, void* d_ws, size_t ws_size,
                              hipStream_t stream)
{
    (void)in_sizes; (void)n_in; (void)out_size; (void)ws_size;
    const float* x   = (const float*)d_in[0];
    const int*   ei  = (const int*)d_in[1];
    const float* ew  = (const float*)d_in[2];
    const float* Wn1 = (const float*)d_in[3];
    const float* bn1 = (const float*)d_in[4];
    const float* Wn2 = (const float*)d_in[5];
    const float* bn2 = (const float*)d_in[6];
    const float* We1 = (const float*)d_in[7];
    const float* be1 = (const float*)d_in[8];
    const float* We2 = (const float*)d_in[9];
    const float* be2 = (const float*)d_in[10];
    const float* eps = (const float*)d_in[11];
    float* out = (float*)d_out;

    float* ws = (float*)d_ws;
    float* adense = ws + OFF_ADENSE;
    int*   cnt    = (int*)(ws + OFF_CNT);
    int*   offs   = (int*)(ws + OFF_OFFS);
    int*   cursor = (int*)(ws + OFF_CURSOR);
    int*   srts   = (int*)(ws + OFF_SRTS);
    float* srtw   = ws + OFF_SRTW;
    float* Pb     = ws + OFF_P;
    float* Qb     = ws + OFF_Q;

    // zero adense + cnt (contiguous)
    (void)hipMemsetAsync(d_ws, 0, (size_t)(4194304 + 4096) * sizeof(float), stream);

    k_count     <<<(CC * EE) / 256, 256, 0, stream>>>(ei, cnt);
    k_scan      <<<1, 256, 0, stream>>>(cnt, offs, cursor);
    k_bucket_adj<<<(CC * EE) / 256, 256, 0, stream>>>(ei, ew, cursor, srts, srtw, adense);
    k_node      <<<NN / 4, 1024, 0, stream>>>(x, offs, srts, srtw,
                                              Wn1, bn1, Wn2, bn2, We1, be1, eps, Pb, Qb);

    dim3 g(NN / 32, NN / 32);
    k_edge_mlp<<<g, 256, 0, stream>>>(Pb, Qb, adense, We1, We2, be2, out);
}